// Round 5
// baseline (458.101 us; speedup 1.0000x reference)
//
#include <hip/hip_runtime.h>

typedef unsigned short ushort;
typedef __bf16 bf16x8 __attribute__((ext_vector_type(8)));
typedef float f32x4 __attribute__((ext_vector_type(4)));

#define F_IN 256
#define CCH  128

// ---------------- helpers ----------------
__device__ __forceinline__ ushort f2bf(float f) {
    union { float f; unsigned i; } u; u.f = f;
    unsigned r = u.i + 0x7fffu + ((u.i >> 16) & 1u);   // RNE
    return (ushort)(r >> 16);
}
__device__ __forceinline__ float2 bf2f2(unsigned u) {
    union { unsigned i; float f; } lo, hi;
    lo.i = u << 16;
    hi.i = u & 0xffff0000u;
    return make_float2(lo.f, hi.f);
}
__device__ __forceinline__ void gload_lds16(const void* g, void* l) {
    __builtin_amdgcn_global_load_lds((const __attribute__((address_space(1))) unsigned*)g,
                                     (__attribute__((address_space(3))) unsigned*)l, 16, 0, 0);
}

// ---------------- K0: weight cvt (w1b PRE-SWIZZLED) + zero deg ----------------
// w1b: within each 32-col k-tile, 8-elem chunk c -> c ^ ((row>>1)&3); gemm stages it with
// linear global_load_lds and applies the same XOR on the ds_read side (both-sides rule).
__global__ __launch_bounds__(256)
void cvt_zero(const float* __restrict__ W1, const float* __restrict__ W2,
              ushort* __restrict__ w1b, ushort* __restrict__ w2b,
              int* __restrict__ deg, int N, int ncvt)
{
    const int blk = blockIdx.x, t = threadIdx.x;
    if (blk < ncvt) {
        int i = blk * 256 + t;
        if (i < CCH * F_IN) {
            int c  = i & 31;
            int cs = c ^ (((i >> 9) & 3) << 3);        // (row>>1)&3, row = i>>8
            w1b[(i & ~31) | cs] = f2bf(W1[i]);
        } else {
            int j = i - CCH * F_IN;
            if (j < CCH * CCH) w2b[j] = f2bf(W2[j]);
        }
        return;
    }
    int i = (blk - ncvt) * 1024 + t * 4;
    if (i + 3 < N) *(int4*)&deg[i] = make_int4(0, 0, 0, 0);
    else { for (int q = 0; q < 4; q++) if (i + q < N) deg[i + q] = 0; }
}

// ---------------- device body: fused GEMM  zq = relu(x@W1^T+b1) @ W2^T ----------------
// [R3 PMC: bank conflicts 3.08M->200K (swizzles verified). VGPR uncapped: R2's (256,4) cap
//  forced VGPR=64 -> 113MB scratch spill. dinv applied in gather, not here.]
__device__ __forceinline__ void gemm_body(unsigned* smem4,
    const float* __restrict__ X, const ushort* __restrict__ W1b,
    const ushort* __restrict__ W2b, const float* __restrict__ b1,
    ushort* __restrict__ Zq, int M, int m0)
{
    ushort* smem = (ushort*)smem4;          // 32768 B: dbuf k-tiles, aliased by Ht[128][128]
    ushort* Ht = smem;
    const int tid  = threadIdx.x;
    const int wave = tid >> 6, lane = tid & 63;
    const int wm = (wave & 1) * 64, wn = (wave >> 1) * 64;
    const int lr = lane & 15, lq = lane >> 4;

    const int arow = tid >> 2;
    const int aq   = tid & 3;

    float4 ar[2][2];
    auto loadX = [&](int k0) {
#pragma unroll
        for (int it = 0; it < 2; it++) {
            int row = arow + it * 64;
            ar[it][0] = make_float4(0.f, 0.f, 0.f, 0.f);
            ar[it][1] = make_float4(0.f, 0.f, 0.f, 0.f);
            if (m0 + row < M) {
                const float* p = &X[(long)(m0 + row) * F_IN + k0 + aq * 8];
                ar[it][0] = *(const float4*)p;
                ar[it][1] = *(const float4*)(p + 4);
            }
        }
    };
    auto writeA = [&](ushort* As) {
#pragma unroll
        for (int it = 0; it < 2; it++) {
            int row = arow + it * 64;
            ushort u[8] = { f2bf(ar[it][0].x), f2bf(ar[it][0].y), f2bf(ar[it][0].z), f2bf(ar[it][0].w),
                            f2bf(ar[it][1].x), f2bf(ar[it][1].y), f2bf(ar[it][1].z), f2bf(ar[it][1].w) };
            *(uint4*)&As[row * 32 + ((aq ^ ((row >> 1) & 3)) << 3)] = *(uint4*)u;
        }
    };
    auto stageB = [&](int k0, ushort* Bs) {
#pragma unroll
        for (int it = 0; it < 2; it++) {
            int r0 = wave * 32 + it * 16;                        // wave-uniform LDS dest
            const ushort* g = &W1b[(long)(r0 + (lane >> 2)) * F_IN + k0 + (lane & 3) * 8];
            gload_lds16(g, &Bs[r0 * 32]);
        }
    };

    // ---- phase A: acc = x @ W1^T (K=256) ----
    f32x4 acc[4][4] = {};
    loadX(0);
    stageB(0, smem + 4096);
    writeA(smem);
    __syncthreads();
    for (int k0 = 0; k0 < F_IN; k0 += 32) {
        const int cur = (k0 >> 5) & 1;
        ushort* As = smem + cur * 8192;
        ushort* Bs = As + 4096;
        const bool more = (k0 + 32 < F_IN);
        if (more) {
            stageB(k0 + 32, smem + (cur ^ 1) * 8192 + 4096);
            loadX(k0 + 32);
        }
        bf16x8 af[4], bfr[4];
#pragma unroll
        for (int t4 = 0; t4 < 4; t4++) {
            int ra = wm + t4 * 16 + lr;
            int rb = wn + t4 * 16 + lr;
            af[t4]  = *(bf16x8*)&As[ra * 32 + ((lq ^ ((ra >> 1) & 3)) << 3)];
            bfr[t4] = *(bf16x8*)&Bs[rb * 32 + ((lq ^ ((rb >> 1) & 3)) << 3)];
        }
#pragma unroll
        for (int i = 0; i < 4; i++)
#pragma unroll
            for (int j = 0; j < 4; j++)
                acc[i][j] = __builtin_amdgcn_mfma_f32_16x16x32_bf16(af[i], bfr[j], acc[i][j], 0, 0, 0);
        if (more) writeA(smem + (cur ^ 1) * 8192);
        __syncthreads();
    }

    // prefetch W2 frags for k0=0
    uint4 wb[2][4];
#pragma unroll
    for (int t4 = 0; t4 < 4; t4++)
        wb[0][t4] = *(const uint4*)&W2b[(long)(wn + t4 * 16 + lr) * CCH + lq * 8];

    // ---- epilogue A: h = relu(acc + b1) -> Ht (swizzled) ----
    {
        float bv[4];
#pragma unroll
        for (int j = 0; j < 4; j++) bv[j] = b1[wn + j * 16 + lr];
#pragma unroll
        for (int i = 0; i < 4; i++)
#pragma unroll
            for (int r = 0; r < 4; r++) {
                int row = wm + i * 16 + lq * 4 + r;
                int rx  = (row & 7) << 3;
#pragma unroll
                for (int j = 0; j < 4; j++)
                    Ht[row * 128 + ((wn + j * 16 + lr) ^ rx)] = f2bf(fmaxf(acc[i][j][r] + bv[j], 0.f));
            }
    }
    __syncthreads();

    // ---- phase B: acc2 = h @ W2^T (K=128), barrier-free ----
    f32x4 acc2[4][4] = {};
#pragma unroll
    for (int kk = 0; kk < 4; kk++) {
        const int k0 = kk * 32;
        if (kk < 3) {
#pragma unroll
            for (int t4 = 0; t4 < 4; t4++)
                wb[(kk + 1) & 1][t4] =
                    *(const uint4*)&W2b[(long)(wn + t4 * 16 + lr) * CCH + k0 + 32 + lq * 8];
        }
        bf16x8 af[4];
#pragma unroll
        for (int t4 = 0; t4 < 4; t4++) {
            int ra = wm + t4 * 16 + lr;
            af[t4] = *(bf16x8*)&Ht[ra * 128 + ((k0 + lq * 8) ^ ((ra & 7) << 3))];
        }
#pragma unroll
        for (int i = 0; i < 4; i++)
#pragma unroll
            for (int j = 0; j < 4; j++)
                acc2[i][j] = __builtin_amdgcn_mfma_f32_16x16x32_bf16(af[i], *(bf16x8*)&wb[kk & 1][j],
                                                                     acc2[i][j], 0, 0, 0);
    }
    __syncthreads();

    // ---- epilogue B: z -> Ht (swizzled) -> coalesced store ----
#pragma unroll
    for (int i = 0; i < 4; i++)
#pragma unroll
        for (int r = 0; r < 4; r++) {
            int row = wm + i * 16 + lq * 4 + r;
            int rx  = (row & 7) << 3;
#pragma unroll
            for (int j = 0; j < 4; j++)
                Ht[row * 128 + ((wn + j * 16 + lr) ^ rx)] = f2bf(acc2[i][j][r]);
        }
    __syncthreads();
    {
        int colq = tid & 15, row0 = tid >> 4;
#pragma unroll
        for (int i = 0; i < 8; i++) {
            int row = row0 + i * 16;
            if (m0 + row < M)
                *(uint4*)&Zq[(long)(m0 + row) * CCH + colq * 8] =
                    *(uint4*)&Ht[row * 128 + ((colq * 8) ^ ((row & 7) << 3))];
        }
    }
}

// ---------------- U1: gemm + per-block degree-count stripe ----------------
// Count work rides in each gemm block's tail: staggered block completion overlaps the
// atomic-bound counting under other blocks' MFMA work, with no occupancy coupling.
__global__ __launch_bounds__(256)
void gemm_count(const float* __restrict__ X, const ushort* __restrict__ W1b,
                const ushort* __restrict__ W2b, const float* __restrict__ b1,
                ushort* __restrict__ Zq, int M,
                const int* __restrict__ dst, int* __restrict__ deg, int E, int eper)
{
    __shared__ unsigned smem4[8192];    // 32 KB
    gemm_body(smem4, X, W1b, W2b, b1, Zq, M, blockIdx.x * 128);
    const int e0 = blockIdx.x * eper;
    const int e1 = min(e0 + eper, E);
    for (int e = e0 + (int)threadIdx.x; e < e1; e += 256)
        atomicAdd(&deg[dst[e]], 1);
}

// ---------------- S2: per-1024-chunk degree sums ----------------
__global__ __launch_bounds__(256)
void scan_sums(const int* __restrict__ deg, int* __restrict__ bsum, int N)
{
    __shared__ int s[256];
    const int t = threadIdx.x;
    int base = blockIdx.x * 1024 + t * 4;
    int v = 0;
    if (base + 3 < N) { int4 d = *(const int4*)&deg[base]; v = d.x + d.y + d.z + d.w; }
    else { for (int q = 0; q < 4; q++) if (base + q < N) v += deg[base + q]; }
    s[t] = v;
    __syncthreads();
    for (int off = 128; off > 0; off >>= 1) {
        if (t < off) s[t] += s[t + off];
        __syncthreads();
    }
    if (t == 0) bsum[blockIdx.x] = s[0];
}

// ---------------- S3: top-level exclusive scan of chunk sums ----------------
__global__ __launch_bounds__(128)
void scan_top(const int* __restrict__ bsum, int* __restrict__ boff, int nb)
{
    __shared__ int s[128];
    const int t = threadIdx.x;
    int carry = 0;
    for (int c = 0; c < nb; c += 128) {
        int idx = c + t;
        int v = (idx < nb) ? bsum[idx] : 0;
        s[t] = v;
        __syncthreads();
        for (int off = 1; off < 128; off <<= 1) {
            int x = (t >= off) ? s[t - off] : 0;
            __syncthreads();
            s[t] += x;
            __syncthreads();
        }
        if (idx < nb) boff[idx] = carry + s[t] - v;
        carry += s[127];
        __syncthreads();
    }
}

// ---------------- S4: finalize rstart / cur / dinv ----------------
__global__ __launch_bounds__(256)
void scan_final(const int* __restrict__ deg, const int* __restrict__ boff,
                int* __restrict__ rstart, int* __restrict__ cur,
                float* __restrict__ dinv, int N, int E)
{
    __shared__ int s[256];
    const int t = threadIdx.x;
    int base = blockIdx.x * 1024 + t * 4;
    int4 d = make_int4(0, 0, 0, 0);
    if (base + 3 < N) d = *(const int4*)&deg[base];
    else {
        if (base + 0 < N) d.x = deg[base + 0];
        if (base + 1 < N) d.y = deg[base + 1];
        if (base + 2 < N) d.z = deg[base + 2];
    }
    int tsum = d.x + d.y + d.z + d.w;
    s[t] = tsum;
    __syncthreads();
    for (int off = 1; off < 256; off <<= 1) {
        int x = (t >= off) ? s[t - off] : 0;
        __syncthreads();
        s[t] += x;
        __syncthreads();
    }
    int excl = boff[blockIdx.x] + s[t] - tsum;
    int r0 = excl, r1 = r0 + d.x, r2 = r1 + d.y, r3 = r2 + d.z;
    if (base + 3 < N) {
        *(int4*)&rstart[base]  = make_int4(r0, r1, r2, r3);
        *(int4*)&cur[base]     = make_int4(r0, r1, r2, r3);
        *(float4*)&dinv[base]  = make_float4(rsqrtf((float)d.x + 1.f), rsqrtf((float)d.y + 1.f),
                                             rsqrtf((float)d.z + 1.f), rsqrtf((float)d.w + 1.f));
    } else {
        int rr[4] = { r0, r1, r2, r3 };
        int dd[4] = { d.x, d.y, d.z, d.w };
        for (int q = 0; q < 4; q++) if (base + q < N) {
            rstart[base + q] = rr[q];
            cur[base + q]    = rr[q];
            dinv[base + q]   = rsqrtf((float)dd[q] + 1.f);
        }
    }
    if (blockIdx.x == 0 && t == 0) rstart[N] = E;
}

// ---------------- S5: scatter edges into CSR (order nondeterministic; sums are assoc-safe) ----
__global__ __launch_bounds__(256)
void scatter(const int* __restrict__ src, const int* __restrict__ dst,
             int* __restrict__ cur, int* __restrict__ csr, int E)
{
    const int stride = gridDim.x * 256;
    for (int e = blockIdx.x * 256 + threadIdx.x; e < E; e += stride) {
        int d = dst[e];
        int slot = atomicAdd(&cur[d], 1);
        csr[slot] = src[e];
    }
}

// ---------------- K6: gather (dinv[src]*dinv[dst] applied here) ----------------
__global__ __launch_bounds__(256)
void gather_nodes(const unsigned* __restrict__ zq, const int* __restrict__ csr,
                  const int* __restrict__ row_start, const float* __restrict__ dinv,
                  const float* __restrict__ b2, float* __restrict__ out, int N)
{
    const int node = blockIdx.x * 4 + (threadIdx.x >> 6);
    const int lane = threadIdx.x & 63;
    if (node >= N) return;

    const float di = dinv[node];
    float2 zs = bf2f2(zq[(long)node * 64 + lane]);
    float acc0 = di * zs.x, acc1 = di * zs.y;      // self-loop: dinv[d]*z[d]

    const int rs = row_start[node];
    const int re = row_start[node + 1];
    int j = rs;
    for (; j + 8 <= re; j += 8) {
        int sI[8]; unsigned zv[8]; float dv[8];
#pragma unroll
        for (int q = 0; q < 8; q++) sI[q] = csr[j + q];
#pragma unroll
        for (int q = 0; q < 8; q++) dv[q] = dinv[sI[q]];
#pragma unroll
        for (int q = 0; q < 8; q++) zv[q] = zq[(long)sI[q] * 64 + lane];
#pragma unroll
        for (int q = 0; q < 8; q++) { float2 f = bf2f2(zv[q]); acc0 += dv[q] * f.x; acc1 += dv[q] * f.y; }
    }
    for (; j < re; j++) {
        int sidx = csr[j];
        float ds = dinv[sidx];
        float2 f = bf2f2(zq[(long)sidx * 64 + lane]);
        acc0 += ds * f.x; acc1 += ds * f.y;
    }

    float2 o;
    o.x = b2[lane * 2 + 0] + di * acc0;
    o.y = b2[lane * 2 + 1] + di * acc1;
    *(float2*)&out[(long)node * CCH + lane * 2] = o;
}

extern "C" void kernel_launch(void* const* d_in, const int* in_sizes, int n_in,
                              void* d_out, int out_size, void* d_ws, size_t ws_size,
                              hipStream_t stream)
{
    const float* x  = (const float*)d_in[0];
    const int*   ei = (const int*)d_in[1];
    const float* W1 = (const float*)d_in[2];
    const float* b1 = (const float*)d_in[3];
    const float* W2 = (const float*)d_in[4];
    const float* b2 = (const float*)d_in[5];
    float* out = (float*)d_out;

    const int N = in_sizes[0] / F_IN;
    const int E = in_sizes[1] / 2;
    const int* src = ei;
    const int* dst = ei + E;

    const int ngrid = (N + 127) / 128;                       // 782 gemm blocks
    const int ncvt  = (CCH * F_IN + CCH * CCH + 255) / 256;  // 192
    const int nz    = (N + 1023) / 1024;                     // 98
    const int eper  = (E + ngrid - 1) / ngrid;               // ~2047 edges per gemm block

    char* ws = (char*)d_ws;
    ushort* zq  = (ushort*)ws; ws += (size_t)N * CCH * 2;
    ushort* w1b = (ushort*)ws; ws += (size_t)CCH * F_IN * 2;
    ushort* w2b = (ushort*)ws; ws += (size_t)CCH * CCH * 2;
    int* csr    = (int*)ws;    ws += (size_t)E * 4;
    int* deg    = (int*)ws;    ws += (size_t)N * 4;
    int* cur    = (int*)ws;    ws += (size_t)N * 4;
    float* dinv = (float*)ws;  ws += (size_t)N * 4;
    int* rstart = (int*)ws;    ws += ((size_t)N + 1) * 4;
    int* bsum   = (int*)ws;    ws += (size_t)nz * 4;
    int* boff   = (int*)ws;    ws += (size_t)nz * 4;

    // K0: weight cvt (pre-swizzled w1b) + zero deg
    cvt_zero<<<ncvt + nz, 256, 0, stream>>>(W1, W2, w1b, w2b, deg, N, ncvt);
    // U1: fused GEMMs + degree count (count stripe rides each block's tail)
    gemm_count<<<ngrid, 256, 0, stream>>>(x, w1b, w2b, b1, zq, N, dst, deg, E, eper);
    // S2-S4: prefix scan -> rstart / cur / dinv
    scan_sums<<<nz, 256, 0, stream>>>(deg, bsum, N);
    scan_top<<<1, 128, 0, stream>>>(bsum, boff, nz);
    scan_final<<<nz, 256, 0, stream>>>(deg, boff, rstart, cur, dinv, N, E);
    // S5: scatter edges into CSR
    scatter<<<1024, 256, 0, stream>>>(src, dst, cur, csr, E);
    // K6: aggregate
    gather_nodes<<<(N + 3) / 4, 256, 0, stream>>>((const unsigned*)zq, csr, rstart, dinv, b2, out, N);
}

// Round 6
// 327.532 us; speedup vs baseline: 1.3986x; 1.3986x over previous
//
#include <hip/hip_runtime.h>

typedef unsigned short ushort;
typedef __bf16 bf16x8 __attribute__((ext_vector_type(8)));
typedef float f32x4 __attribute__((ext_vector_type(4)));

#define F_IN 256
#define CCH  128
#define BSH  7
#define BNODES 128
#define NBUCK 1024
#define CHUNK 2048

// ---------------- helpers ----------------
__device__ __forceinline__ ushort f2bf(float f) {
    union { float f; unsigned i; } u; u.f = f;
    unsigned r = u.i + 0x7fffu + ((u.i >> 16) & 1u);   // RNE
    return (ushort)(r >> 16);
}
__device__ __forceinline__ float2 bf2f2(unsigned u) {
    union { unsigned i; float f; } lo, hi;
    lo.i = u << 16;
    hi.i = u & 0xffff0000u;
    return make_float2(lo.f, hi.f);
}
__device__ __forceinline__ void gload_lds16(const void* g, void* l) {
    __builtin_amdgcn_global_load_lds((const __attribute__((address_space(1))) unsigned*)g,
                                     (__attribute__((address_space(3))) unsigned*)l, 16, 0, 0);
}

// ---------------- K0: weight cvt (w1b PRE-SWIZZLED) ----------------
// Must be its own kernel: gemm blocks in U0 need w1b complete; union blocks have no ordering.
__global__ __launch_bounds__(256)
void cvt_w(const float* __restrict__ W1, const float* __restrict__ W2,
           ushort* __restrict__ w1b, ushort* __restrict__ w2b)
{
    int i = blockIdx.x * 256 + threadIdx.x;
    if (i < CCH * F_IN) {
        int c  = i & 31;
        int cs = c ^ (((i >> 9) & 3) << 3);        // (row>>1)&3, row = i>>8
        w1b[(i & ~31) | cs] = f2bf(W1[i]);
    } else {
        int j = i - CCH * F_IN;
        if (j < CCH * CCH) w2b[j] = f2bf(W2[j]);
    }
}

// ---------------- device body: per-chunk histogram (dual layout) ----------------
__device__ __forceinline__ void hist_body(unsigned* smem4,
    const int* __restrict__ dst, int* __restrict__ histC, int* __restrict__ histT,
    int E, int ncp, int blk)
{
    int* h = (int*)smem4;                  // NBUCK ints = 4 KB
    const int t = threadIdx.x;
    for (int i = t; i < NBUCK; i += 256) h[i] = 0;
    __syncthreads();
    int cb = blk * CHUNK, ce = min(cb + CHUNK, E);
    for (int e = cb + t; e < ce; e += 256)
        atomicAdd(&h[dst[e] >> BSH], 1);
    __syncthreads();
    for (int i = t; i < NBUCK; i += 256) {
        int v = h[i];
        histC[blk * NBUCK + i] = v;     // chunk-major (partition)
        histT[i * ncp + blk]   = v;     // bucket-major (scan)
    }
}

// ---------------- K2: per-bucket cross-chunk prefix (one wave per bucket) ----------------
__global__ __launch_bounds__(256)
void scan_buckets(const int* __restrict__ histT, int* __restrict__ prefT,
                  int* __restrict__ btot, int nchunks, int ncp)
{
    const int b = blockIdx.x * 4 + (threadIdx.x >> 6);
    const int lane = threadIdx.x & 63;
    int carry = 0;
    for (int c = 0; c < nchunks; c += 64) {
        int idx = c + lane;
        int v = (idx < nchunks) ? histT[b * ncp + idx] : 0;
        int inc = v;
#pragma unroll
        for (int off = 1; off < 64; off <<= 1) {
            int x = __shfl_up(inc, off, 64);
            if (lane >= off) inc += x;
        }
        if (idx < nchunks) prefT[b * ncp + idx] = carry + inc - v;
        carry += __shfl(inc, 63, 64);
    }
    if (lane == 0) btot[b] = carry;
}

// ---------------- device body: partition (deterministic slots) ----------------
// LDS carve (u32): lbase|lcur|rb2|base_s (4x1024) ssum(256) sp(2048) sb(1024) = 7424 <= 8192
__device__ __forceinline__ void partition_body(unsigned* smem4,
    const int* __restrict__ src, const int* __restrict__ dst,
    const int* __restrict__ histC, const int* __restrict__ prefT,
    const int* __restrict__ btot, int* __restrict__ gbase,
    unsigned* __restrict__ pairs, int E, int ncp, int blk)
{
    int* lbase  = (int*)smem4;
    int* lcur   = lbase + NBUCK;
    int* rb2    = lcur + NBUCK;
    int* base_s = rb2 + NBUCK;
    int* ssum   = base_s + NBUCK;          // 256
    unsigned* sp = (unsigned*)(ssum + 256); // 2048
    ushort* sb  = (ushort*)(sp + CHUNK);    // 2048 ushort
    const int t = threadIdx.x;

    int4 cv = *(const int4*)&histC[blk * NBUCK + 4 * t];
    int tsum = cv.x + cv.y + cv.z + cv.w;
    ssum[t] = tsum;
    __syncthreads();
    for (int off = 1; off < 256; off <<= 1) {
        int x = (t >= off) ? ssum[t - off] : 0;
        __syncthreads();
        ssum[t] += x;
        __syncthreads();
    }
    int texcl = ssum[t] - tsum;
    lbase[4 * t]     = texcl;
    lbase[4 * t + 1] = texcl + cv.x;
    lbase[4 * t + 2] = texcl + cv.x + cv.y;
    lbase[4 * t + 3] = texcl + cv.x + cv.y + cv.z;
    lcur[4 * t]     = lbase[4 * t];
    lcur[4 * t + 1] = lbase[4 * t + 1];
    lcur[4 * t + 2] = lbase[4 * t + 2];
    lcur[4 * t + 3] = lbase[4 * t + 3];
    __syncthreads();

    int4 bt = *(const int4*)&btot[4 * t];
    int bsum = bt.x + bt.y + bt.z + bt.w;
    ssum[t] = bsum;
    __syncthreads();
    for (int off = 1; off < 256; off <<= 1) {
        int x = (t >= off) ? ssum[t - off] : 0;
        __syncthreads();
        ssum[t] += x;
        __syncthreads();
    }
    int bexcl = ssum[t] - bsum;
    base_s[4 * t]     = bexcl;
    base_s[4 * t + 1] = bexcl + bt.x;
    base_s[4 * t + 2] = bexcl + bt.x + bt.y;
    base_s[4 * t + 3] = bexcl + bt.x + bt.y + bt.z;
    if (blk == 0) {
        *(int4*)&gbase[4 * t] = *(int4*)&base_s[4 * t];
        if (t == 255) gbase[NBUCK] = ssum[255];
    }
    __syncthreads();
    for (int i = t; i < NBUCK; i += 256)
        rb2[i] = base_s[i] + prefT[i * ncp + blk];
    __syncthreads();

    const int cb = blk * CHUNK, ce = min(cb + CHUNK, E);
    for (int e = cb + t; e < ce; e += 256) {
        int d = dst[e];
        int b = d >> BSH;
        unsigned packed = ((unsigned)src[e] << BSH) | (unsigned)(d & (BNODES - 1));
        int p = atomicAdd(&lcur[b], 1);
        sp[p] = packed;
        sb[p] = (ushort)b;
    }
    __syncthreads();
    const int cnt = ce - cb;
    for (int i = t; i < cnt; i += 256) {
        int b = sb[i];
        pairs[rb2[b] + (i - lbase[b])] = sp[i];
    }
}

// ---------------- device body: per-bucket CSR finalize ----------------
__device__ __forceinline__ void csr_body(unsigned* smem4,
    const unsigned* __restrict__ pairs, const int* __restrict__ base,
    int* __restrict__ row_start, float* __restrict__ dinv,
    unsigned* __restrict__ csr, int N, int E, int b, int lastb)
{
    int* deg = (int*)smem4;
    int* s   = deg + BNODES;
    int* cur = s + BNODES;
    const int t = threadIdx.x;
    if (t < BNODES) deg[t] = 0;
    __syncthreads();
    const int rb = base[b], re = base[b + 1];
    for (int e = rb + t; e < re; e += 256)
        atomicAdd(&deg[pairs[e] & (BNODES - 1)], 1);
    __syncthreads();
    int v = (t < BNODES) ? deg[t] : 0;
    if (t < BNODES) s[t] = v;
    __syncthreads();
    for (int off = 1; off < BNODES; off <<= 1) {
        int x = (t >= off && t < BNODES) ? s[t - off] : 0;
        __syncthreads();
        if (t < BNODES) s[t] += x;
        __syncthreads();
    }
    const int n0 = b << BSH;
    if (t < BNODES) {
        int excl = s[t] - v;
        cur[t] = excl;
        if (n0 + t < N) {
            row_start[n0 + t] = rb + excl;
            dinv[n0 + t] = rsqrtf((float)v + 1.0f);
        }
    }
    if (b == lastb && t == 0) row_start[N] = E;
    __syncthreads();
    for (int e = rb + t; e < re; e += 256) {
        unsigned p = pairs[e];
        int l = p & (BNODES - 1);
        int slot = atomicAdd(&cur[l], 1);
        csr[rb + slot] = p >> BSH;
    }
}

// ---------------- device body: fused GEMM  zq = relu(x@W1^T+b1) @ W2^T ----------------
// [R3 PMC: bank conflicts 3.08M->200K (swizzles verified). VGPR uncapped: R2's (256,4) cap
//  forced VGPR=64 -> 113MB scratch spill. dinv applied in gather. Row guard -> clamp:
//  padded rows compute duplicates of row M-1, never stored.]
__device__ __forceinline__ void gemm_body(unsigned* smem4,
    const float* __restrict__ X, const ushort* __restrict__ W1b,
    const ushort* __restrict__ W2b, const float* __restrict__ b1,
    ushort* __restrict__ Zq, int M, int m0)
{
    ushort* smem = (ushort*)smem4;          // 32768 B: dbuf k-tiles, aliased by Ht[128][128]
    ushort* Ht = smem;
    const int tid  = threadIdx.x;
    const int wave = tid >> 6, lane = tid & 63;
    const int wm = (wave & 1) * 64, wn = (wave >> 1) * 64;
    const int lr = lane & 15, lq = lane >> 4;

    const int arow = tid >> 2;
    const int aq   = tid & 3;

    float4 ar[2][2];
    auto loadX = [&](int k0) {
#pragma unroll
        for (int it = 0; it < 2; it++) {
            int grow = min(m0 + arow + it * 64, M - 1);        // clamp, no branch
            const float* p = &X[(long)grow * F_IN + k0 + aq * 8];
            ar[it][0] = *(const float4*)p;
            ar[it][1] = *(const float4*)(p + 4);
        }
    };
    auto writeA = [&](ushort* As) {
#pragma unroll
        for (int it = 0; it < 2; it++) {
            int row = arow + it * 64;
            ushort u[8] = { f2bf(ar[it][0].x), f2bf(ar[it][0].y), f2bf(ar[it][0].z), f2bf(ar[it][0].w),
                            f2bf(ar[it][1].x), f2bf(ar[it][1].y), f2bf(ar[it][1].z), f2bf(ar[it][1].w) };
            *(uint4*)&As[row * 32 + ((aq ^ ((row >> 1) & 3)) << 3)] = *(uint4*)u;
        }
    };
    auto stageB = [&](int k0, ushort* Bs) {
#pragma unroll
        for (int it = 0; it < 2; it++) {
            int r0 = wave * 32 + it * 16;                        // wave-uniform LDS dest
            const ushort* g = &W1b[(long)(r0 + (lane >> 2)) * F_IN + k0 + (lane & 3) * 8];
            gload_lds16(g, &Bs[r0 * 32]);
        }
    };

    // ---- phase A: acc = x @ W1^T (K=256) ----
    f32x4 acc[4][4] = {};
    loadX(0);
    stageB(0, smem + 4096);
    writeA(smem);
    __syncthreads();
    for (int k0 = 0; k0 < F_IN; k0 += 32) {
        const int cur = (k0 >> 5) & 1;
        ushort* As = smem + cur * 8192;
        ushort* Bs = As + 4096;
        const bool more = (k0 + 32 < F_IN);
        if (more) {
            stageB(k0 + 32, smem + (cur ^ 1) * 8192 + 4096);
            loadX(k0 + 32);
        }
        bf16x8 af[4], bfr[4];
#pragma unroll
        for (int t4 = 0; t4 < 4; t4++) {
            int ra = wm + t4 * 16 + lr;
            int rb = wn + t4 * 16 + lr;
            af[t4]  = *(bf16x8*)&As[ra * 32 + ((lq ^ ((ra >> 1) & 3)) << 3)];
            bfr[t4] = *(bf16x8*)&Bs[rb * 32 + ((lq ^ ((rb >> 1) & 3)) << 3)];
        }
#pragma unroll
        for (int i = 0; i < 4; i++)
#pragma unroll
            for (int j = 0; j < 4; j++)
                acc[i][j] = __builtin_amdgcn_mfma_f32_16x16x32_bf16(af[i], bfr[j], acc[i][j], 0, 0, 0);
        if (more) writeA(smem + (cur ^ 1) * 8192);
        __syncthreads();
    }

    // prefetch W2 frags for k0=0
    uint4 wb[2][4];
#pragma unroll
    for (int t4 = 0; t4 < 4; t4++)
        wb[0][t4] = *(const uint4*)&W2b[(long)(wn + t4 * 16 + lr) * CCH + lq * 8];

    // ---- epilogue A: h = relu(acc + b1) -> Ht (swizzled) ----
    {
        float bv[4];
#pragma unroll
        for (int j = 0; j < 4; j++) bv[j] = b1[wn + j * 16 + lr];
#pragma unroll
        for (int i = 0; i < 4; i++)
#pragma unroll
            for (int r = 0; r < 4; r++) {
                int row = wm + i * 16 + lq * 4 + r;
                int rx  = (row & 7) << 3;
#pragma unroll
                for (int j = 0; j < 4; j++)
                    Ht[row * 128 + ((wn + j * 16 + lr) ^ rx)] = f2bf(fmaxf(acc[i][j][r] + bv[j], 0.f));
            }
    }
    __syncthreads();

    // ---- phase B: acc2 = h @ W2^T (K=128), barrier-free ----
    f32x4 acc2[4][4] = {};
#pragma unroll
    for (int kk = 0; kk < 4; kk++) {
        const int k0 = kk * 32;
        if (kk < 3) {
#pragma unroll
            for (int t4 = 0; t4 < 4; t4++)
                wb[(kk + 1) & 1][t4] =
                    *(const uint4*)&W2b[(long)(wn + t4 * 16 + lr) * CCH + k0 + 32 + lq * 8];
        }
        bf16x8 af[4];
#pragma unroll
        for (int t4 = 0; t4 < 4; t4++) {
            int ra = wm + t4 * 16 + lr;
            af[t4] = *(bf16x8*)&Ht[ra * 128 + ((k0 + lq * 8) ^ ((ra & 7) << 3))];
        }
#pragma unroll
        for (int i = 0; i < 4; i++)
#pragma unroll
            for (int j = 0; j < 4; j++)
                acc2[i][j] = __builtin_amdgcn_mfma_f32_16x16x32_bf16(af[i], *(bf16x8*)&wb[kk & 1][j],
                                                                     acc2[i][j], 0, 0, 0);
    }
    __syncthreads();

    // ---- epilogue B: z -> Ht (swizzled) -> coalesced store ----
#pragma unroll
    for (int i = 0; i < 4; i++)
#pragma unroll
        for (int r = 0; r < 4; r++) {
            int row = wm + i * 16 + lq * 4 + r;
            int rx  = (row & 7) << 3;
#pragma unroll
            for (int j = 0; j < 4; j++)
                Ht[row * 128 + ((wn + j * 16 + lr) ^ rx)] = f2bf(acc2[i][j][r]);
        }
    __syncthreads();
    {
        int colq = tid & 15, row0 = tid >> 4;
#pragma unroll
        for (int i = 0; i < 8; i++) {
            int row = row0 + i * 16;
            if (m0 + row < M)
                *(uint4*)&Zq[(long)(m0 + row) * CCH + colq * 8] =
                    *(uint4*)&Ht[row * 128 + ((colq * 8) ^ ((row & 7) << 3))];
        }
    }
}

// ---------------- U0: gemm third A ∪ histogram ----------------
__global__ __launch_bounds__(256)
void u_gemm_hist(const float* __restrict__ X, const ushort* __restrict__ W1b,
                 const ushort* __restrict__ W2b, const float* __restrict__ b1,
                 ushort* __restrict__ Zq, int M, int ngA,
                 const int* __restrict__ dst, int* __restrict__ histC,
                 int* __restrict__ histT, int E, int ncp)
{
    __shared__ unsigned smem4[8192];    // 32 KB
    if ((int)blockIdx.x < ngA)
        gemm_body(smem4, X, W1b, W2b, b1, Zq, M, blockIdx.x * 128);
    else
        hist_body(smem4, dst, histC, histT, E, ncp, blockIdx.x - ngA);
}

// ---------------- U1: gemm third B ∪ partition ----------------
__global__ __launch_bounds__(256)
void u_gemm_part(const int* __restrict__ src, const int* __restrict__ dst,
                 const int* __restrict__ histC, const int* __restrict__ prefT,
                 const int* __restrict__ btot, int* __restrict__ gbase,
                 unsigned* __restrict__ pairs, int E, int ncp, int ngA, int ngB,
                 const float* __restrict__ X, const ushort* __restrict__ W1b,
                 const ushort* __restrict__ W2b, const float* __restrict__ b1,
                 ushort* __restrict__ Zq, int M)
{
    __shared__ unsigned smem4[8192];
    if ((int)blockIdx.x < ngB)
        gemm_body(smem4, X, W1b, W2b, b1, Zq, M, (ngA + blockIdx.x) * 128);
    else
        partition_body(smem4, src, dst, histC, prefT, btot, gbase, pairs, E, ncp,
                       blockIdx.x - ngB);
}

// ---------------- U2: gemm third C ∪ bucket CSR ----------------
__global__ __launch_bounds__(256)
void u_gemm_csr(const unsigned* __restrict__ pairs, const int* __restrict__ base,
                int* __restrict__ row_start, float* __restrict__ dinv,
                unsigned* __restrict__ csr, int N, int E, int ngAB, int ngC, int nbuck,
                const float* __restrict__ X, const ushort* __restrict__ W1b,
                const ushort* __restrict__ W2b, const float* __restrict__ b1,
                ushort* __restrict__ Zq, int M)
{
    __shared__ unsigned smem4[8192];
    if ((int)blockIdx.x < ngC)
        gemm_body(smem4, X, W1b, W2b, b1, Zq, M, (ngAB + blockIdx.x) * 128);
    else
        csr_body(smem4, pairs, base, row_start, dinv, csr, N, E,
                 blockIdx.x - ngC, nbuck - 1);
}

// ---------------- K6: gather (dinv[src]*dinv[dst] applied here) ----------------
__global__ __launch_bounds__(256)
void gather_nodes(const unsigned* __restrict__ zq, const unsigned* __restrict__ csr,
                  const int* __restrict__ row_start, const float* __restrict__ dinv,
                  const float* __restrict__ b2, float* __restrict__ out, int N)
{
    const int node = blockIdx.x * 4 + (threadIdx.x >> 6);
    const int lane = threadIdx.x & 63;
    if (node >= N) return;

    const float di = dinv[node];
    float2 zs = bf2f2(zq[(long)node * 64 + lane]);
    float acc0 = di * zs.x, acc1 = di * zs.y;      // self-loop: dinv[d]*z[d]

    const int rs = row_start[node];
    const int re = row_start[node + 1];
    int j = rs;
    for (; j + 8 <= re; j += 8) {
        unsigned sI[8], zv[8];
        float dv[8];
#pragma unroll
        for (int q = 0; q < 8; q++) sI[q] = csr[j + q];
#pragma unroll
        for (int q = 0; q < 8; q++) dv[q] = dinv[sI[q]];
#pragma unroll
        for (int q = 0; q < 8; q++) zv[q] = zq[(long)sI[q] * 64 + lane];
#pragma unroll
        for (int q = 0; q < 8; q++) { float2 f = bf2f2(zv[q]); acc0 += dv[q] * f.x; acc1 += dv[q] * f.y; }
    }
    for (; j < re; j++) {
        unsigned s = csr[j];
        float ds = dinv[s];
        float2 f = bf2f2(zq[(long)s * 64 + lane]);
        acc0 += ds * f.x; acc1 += ds * f.y;
    }

    float2 o;
    o.x = b2[lane * 2 + 0] + di * acc0;
    o.y = b2[lane * 2 + 1] + di * acc1;
    *(float2*)&out[(long)node * CCH + lane * 2] = o;
}

extern "C" void kernel_launch(void* const* d_in, const int* in_sizes, int n_in,
                              void* d_out, int out_size, void* d_ws, size_t ws_size,
                              hipStream_t stream)
{
    const float* x  = (const float*)d_in[0];
    const int*   ei = (const int*)d_in[1];
    const float* W1 = (const float*)d_in[2];
    const float* b1 = (const float*)d_in[3];
    const float* W2 = (const float*)d_in[4];
    const float* b2 = (const float*)d_in[5];
    float* out = (float*)d_out;

    const int N = in_sizes[0] / F_IN;
    const int E = in_sizes[1] / 2;
    const int* src = ei;
    const int* dst = ei + E;

    const int nchunks = (E + CHUNK - 1) / CHUNK;        // 782
    const int ncp     = (nchunks + 63) & ~63;           // 832
    const int nbuck   = (N + BNODES - 1) / BNODES;      // 782
    const int ngrid   = (N + 127) / 128;                // 782
    const int ngA     = (ngrid + 2) / 3;                // 261 (gemm third A)
    const int ngB     = (ngrid - ngA + 1) / 2;          // 261 (third B)
    const int ngC     = ngrid - ngA - ngB;              // 260 (third C)
    const int ncvt    = (CCH * F_IN + CCH * CCH + 255) / 256;

    char* ws = (char*)d_ws;
    ushort* zq    = (ushort*)ws;   ws += (size_t)N * CCH * 2;
    ushort* w1b   = (ushort*)ws;   ws += (size_t)CCH * F_IN * 2;
    ushort* w2b   = (ushort*)ws;   ws += (size_t)CCH * CCH * 2;
    unsigned* prs = (unsigned*)ws; ws += (size_t)E * 4;
    unsigned* csr = (unsigned*)ws; ws += (size_t)E * 4;
    int* rstart   = (int*)ws;      ws += ((size_t)N + 1) * 4;
    float* dinv   = (float*)ws;    ws += (size_t)N * 4;
    int* histC    = (int*)ws;      ws += (size_t)nchunks * NBUCK * 4;
    int* histT    = (int*)ws;      ws += (size_t)NBUCK * ncp * 4;
    int* prefT    = (int*)ws;      ws += (size_t)NBUCK * ncp * 4;
    int* btot     = (int*)ws;      ws += NBUCK * 4;
    int* gbase    = (int*)ws;      ws += (NBUCK + 1) * 4;

    // K0: weight cvt (pre-swizzled w1b) — must complete before any gemm block
    cvt_w<<<ncvt, 256, 0, stream>>>(W1, W2, w1b, w2b);
    // U0: gemm-third-A ∪ per-chunk histogram
    u_gemm_hist<<<ngA + nchunks, 256, 0, stream>>>(x, w1b, w2b, b1, zq, N, ngA,
                                                   dst, histC, histT, E, ncp);
    // K2: bucket scan
    scan_buckets<<<NBUCK / 4, 256, 0, stream>>>(histT, prefT, btot, nchunks, ncp);
    // U1: gemm-third-B ∪ partition
    u_gemm_part<<<ngB + nchunks, 256, 0, stream>>>(src, dst, histC, prefT, btot, gbase, prs,
                                                   E, ncp, ngA, ngB, x, w1b, w2b, b1, zq, N);
    // U2: gemm-third-C ∪ bucket-CSR
    u_gemm_csr<<<ngC + nbuck, 256, 0, stream>>>(prs, gbase, rstart, dinv, csr, N, E,
                                                ngA + ngB, ngC, nbuck, x, w1b, w2b, b1, zq, N);
    // K6: aggregate (applies dinv[src] * dinv[dst])
    gather_nodes<<<(N + 3) / 4, 256, 0, stream>>>((const unsigned*)zq, csr, rstart, dinv, b2, out, N);
}

// Round 7
// 314.464 us; speedup vs baseline: 1.4568x; 1.0416x over previous
//
#include <hip/hip_runtime.h>

typedef unsigned short ushort;
typedef __bf16 bf16x8 __attribute__((ext_vector_type(8)));
typedef float f32x4 __attribute__((ext_vector_type(4)));

#define F_IN 256
#define CCH  128
#define BSH  7
#define BNODES 128
#define NBUCK 1024
#define CHUNK 2048

// ---------------- helpers ----------------
__device__ __forceinline__ ushort f2bf(float f) {
    union { float f; unsigned i; } u; u.f = f;
    unsigned r = u.i + 0x7fffu + ((u.i >> 16) & 1u);   // RNE
    return (ushort)(r >> 16);
}
__device__ __forceinline__ float2 bf2f2(unsigned u) {
    union { unsigned i; float f; } lo, hi;
    lo.i = u << 16;
    hi.i = u & 0xffff0000u;
    return make_float2(lo.f, hi.f);
}
__device__ __forceinline__ void gload_lds16(const void* g, void* l) {
    __builtin_amdgcn_global_load_lds((const __attribute__((address_space(1))) unsigned*)g,
                                     (__attribute__((address_space(3))) unsigned*)l, 16, 0, 0);
}

// ---------------- K1: per-chunk histogram (dual layout) + weight cvt ----------------
// histT is TILED: [(b>>4)][chunk][b&15] so each 64B line = 16 buckets of ONE chunk
// (single-writer; the old [b*ncp+c] layout had 16 XCDs ping-ponging every line).
// w1b PRE-SWIZZLED: within each 32-col k-tile, chunk c -> c ^ ((row>>1)&3).
__global__ __launch_bounds__(256)
void hist_cvt(const int* __restrict__ dst, int* __restrict__ histC, int* __restrict__ histT,
              int E, int nchunks, int ncp,
              const float* __restrict__ W1, const float* __restrict__ W2,
              ushort* __restrict__ w1b, ushort* __restrict__ w2b)
{
    const int blk = blockIdx.x, t = threadIdx.x;
    if (blk >= nchunks) {
        int i = (blk - nchunks) * 256 + t;
        if (i < CCH * F_IN) {
            int c  = i & 31;
            int cs = c ^ (((i >> 9) & 3) << 3);        // (row>>1)&3, row = i>>8
            w1b[(i & ~31) | cs] = f2bf(W1[i]);
        } else {
            int j = i - CCH * F_IN;
            if (j < CCH * CCH) w2b[j] = f2bf(W2[j]);
        }
        return;
    }
    __shared__ int h[NBUCK];
    for (int i = t; i < NBUCK; i += 256) h[i] = 0;
    __syncthreads();
    int cb = blk * CHUNK, ce = min(cb + CHUNK, E);
    for (int e = cb + t; e < ce; e += 256)
        atomicAdd(&h[dst[e] >> BSH], 1);
    __syncthreads();
    const int ncp16 = ncp * 16;
    for (int i = t; i < NBUCK; i += 256) {
        int v = h[i];
        histC[blk * NBUCK + i] = v;                            // chunk-major (partition)
        histT[(i >> 4) * ncp16 + blk * 16 + (i & 15)] = v;     // tiled (scan)
    }
}

// ---------------- K2: per-bucket cross-chunk prefix (one wave per bucket) ----------------
// Reads tiled histT; writes prefT in [b*ncp+c] (dense per wave -> single-writer lines).
__global__ __launch_bounds__(256)
void scan_buckets(const int* __restrict__ histT, int* __restrict__ prefT,
                  int* __restrict__ btot, int nchunks, int ncp)
{
    const int b = blockIdx.x * 4 + (threadIdx.x >> 6);
    const int lane = threadIdx.x & 63;
    const int tbase = (b >> 4) * (ncp * 16) + (b & 15);
    int carry = 0;
    for (int c = 0; c < nchunks; c += 64) {
        int idx = c + lane;
        int v = (idx < nchunks) ? histT[tbase + idx * 16] : 0;
        int inc = v;
#pragma unroll
        for (int off = 1; off < 64; off <<= 1) {
            int x = __shfl_up(inc, off, 64);
            if (lane >= off) inc += x;
        }
        if (idx < nchunks) prefT[b * ncp + idx] = carry + inc - v;
        carry += __shfl(inc, 63, 64);
    }
    if (lane == 0) btot[b] = carry;
}

// ---------------- device body: partition (deterministic slots) ----------------
// LDS carve (u32): lbase|lcur|rb2|base_s (4x1024) ssum(256) sp(2048) sb(1024) = 7424 <= 8192
__device__ __forceinline__ void partition_body(unsigned* smem4,
    const int* __restrict__ src, const int* __restrict__ dst,
    const int* __restrict__ histC, const int* __restrict__ prefT,
    const int* __restrict__ btot, int* __restrict__ gbase,
    unsigned* __restrict__ pairs, int E, int ncp, int blk)
{
    int* lbase  = (int*)smem4;
    int* lcur   = lbase + NBUCK;
    int* rb2    = lcur + NBUCK;
    int* base_s = rb2 + NBUCK;
    int* ssum   = base_s + NBUCK;          // 256
    unsigned* sp = (unsigned*)(ssum + 256); // 2048
    ushort* sb  = (ushort*)(sp + CHUNK);    // 2048 ushort
    const int t = threadIdx.x;

    int4 cv = *(const int4*)&histC[blk * NBUCK + 4 * t];
    int tsum = cv.x + cv.y + cv.z + cv.w;
    ssum[t] = tsum;
    __syncthreads();
    for (int off = 1; off < 256; off <<= 1) {
        int x = (t >= off) ? ssum[t - off] : 0;
        __syncthreads();
        ssum[t] += x;
        __syncthreads();
    }
    int texcl = ssum[t] - tsum;
    lbase[4 * t]     = texcl;
    lbase[4 * t + 1] = texcl + cv.x;
    lbase[4 * t + 2] = texcl + cv.x + cv.y;
    lbase[4 * t + 3] = texcl + cv.x + cv.y + cv.z;
    lcur[4 * t]     = lbase[4 * t];
    lcur[4 * t + 1] = lbase[4 * t + 1];
    lcur[4 * t + 2] = lbase[4 * t + 2];
    lcur[4 * t + 3] = lbase[4 * t + 3];
    __syncthreads();

    int4 bt = *(const int4*)&btot[4 * t];
    int bsum = bt.x + bt.y + bt.z + bt.w;
    ssum[t] = bsum;
    __syncthreads();
    for (int off = 1; off < 256; off <<= 1) {
        int x = (t >= off) ? ssum[t - off] : 0;
        __syncthreads();
        ssum[t] += x;
        __syncthreads();
    }
    int bexcl = ssum[t] - bsum;
    base_s[4 * t]     = bexcl;
    base_s[4 * t + 1] = bexcl + bt.x;
    base_s[4 * t + 2] = bexcl + bt.x + bt.y;
    base_s[4 * t + 3] = bexcl + bt.x + bt.y + bt.z;
    if (blk == 0) {
        *(int4*)&gbase[4 * t] = *(int4*)&base_s[4 * t];
        if (t == 255) gbase[NBUCK] = ssum[255];
    }
    __syncthreads();
    for (int i = t; i < NBUCK; i += 256)
        rb2[i] = base_s[i] + prefT[i * ncp + blk];
    __syncthreads();

    const int cb = blk * CHUNK, ce = min(cb + CHUNK, E);
    for (int e = cb + t; e < ce; e += 256) {
        int d = dst[e];
        int b = d >> BSH;
        unsigned packed = ((unsigned)src[e] << BSH) | (unsigned)(d & (BNODES - 1));
        int p = atomicAdd(&lcur[b], 1);
        sp[p] = packed;
        sb[p] = (ushort)b;
    }
    __syncthreads();
    const int cnt = ce - cb;
    for (int i = t; i < cnt; i += 256) {
        int b = sb[i];
        pairs[rb2[b] + (i - lbase[b])] = sp[i];
    }
}

// ---------------- device body: per-bucket CSR finalize ----------------
__device__ __forceinline__ void csr_body(unsigned* smem4,
    const unsigned* __restrict__ pairs, const int* __restrict__ base,
    int* __restrict__ row_start, float* __restrict__ dinv,
    unsigned* __restrict__ csr, int N, int E, int b, int lastb)
{
    int* deg = (int*)smem4;
    int* s   = deg + BNODES;
    int* cur = s + BNODES;
    const int t = threadIdx.x;
    if (t < BNODES) deg[t] = 0;
    __syncthreads();
    const int rb = base[b], re = base[b + 1];
    for (int e = rb + t; e < re; e += 256)
        atomicAdd(&deg[pairs[e] & (BNODES - 1)], 1);
    __syncthreads();
    int v = (t < BNODES) ? deg[t] : 0;
    if (t < BNODES) s[t] = v;
    __syncthreads();
    for (int off = 1; off < BNODES; off <<= 1) {
        int x = (t >= off && t < BNODES) ? s[t - off] : 0;
        __syncthreads();
        if (t < BNODES) s[t] += x;
        __syncthreads();
    }
    const int n0 = b << BSH;
    if (t < BNODES) {
        int excl = s[t] - v;
        cur[t] = excl;
        if (n0 + t < N) {
            row_start[n0 + t] = rb + excl;
            dinv[n0 + t] = rsqrtf((float)v + 1.0f);
        }
    }
    if (b == lastb && t == 0) row_start[N] = E;
    __syncthreads();
    for (int e = rb + t; e < re; e += 256) {
        unsigned p = pairs[e];
        int l = p & (BNODES - 1);
        int slot = atomicAdd(&cur[l], 1);
        csr[rb + slot] = p >> BSH;
    }
}

// ---------------- device body: fused GEMM  zq = relu(x@W1^T+b1) @ W2^T ----------------
// [R3 PMC: bank conflicts 3.08M->200K (swizzles verified). VGPR uncapped: R2's (256,4) cap
//  forced VGPR=64 -> 113MB scratch spill. dinv applied in gather. Row clamp (R6-proven).]
__device__ __forceinline__ void gemm_body(unsigned* smem4,
    const float* __restrict__ X, const ushort* __restrict__ W1b,
    const ushort* __restrict__ W2b, const float* __restrict__ b1,
    ushort* __restrict__ Zq, int M, int m0)
{
    ushort* smem = (ushort*)smem4;          // 32768 B: dbuf k-tiles, aliased by Ht[128][128]
    ushort* Ht = smem;
    const int tid  = threadIdx.x;
    const int wave = tid >> 6, lane = tid & 63;
    const int wm = (wave & 1) * 64, wn = (wave >> 1) * 64;
    const int lr = lane & 15, lq = lane >> 4;

    const int arow = tid >> 2;
    const int aq   = tid & 3;

    float4 ar[2][2];
    auto loadX = [&](int k0) {
#pragma unroll
        for (int it = 0; it < 2; it++) {
            int grow = min(m0 + arow + it * 64, M - 1);        // clamp, no branch
            const float* p = &X[(long)grow * F_IN + k0 + aq * 8];
            ar[it][0] = *(const float4*)p;
            ar[it][1] = *(const float4*)(p + 4);
        }
    };
    auto writeA = [&](ushort* As) {
#pragma unroll
        for (int it = 0; it < 2; it++) {
            int row = arow + it * 64;
            ushort u[8] = { f2bf(ar[it][0].x), f2bf(ar[it][0].y), f2bf(ar[it][0].z), f2bf(ar[it][0].w),
                            f2bf(ar[it][1].x), f2bf(ar[it][1].y), f2bf(ar[it][1].z), f2bf(ar[it][1].w) };
            *(uint4*)&As[row * 32 + ((aq ^ ((row >> 1) & 3)) << 3)] = *(uint4*)u;
        }
    };
    auto stageB = [&](int k0, ushort* Bs) {
#pragma unroll
        for (int it = 0; it < 2; it++) {
            int r0 = wave * 32 + it * 16;                        // wave-uniform LDS dest
            const ushort* g = &W1b[(long)(r0 + (lane >> 2)) * F_IN + k0 + (lane & 3) * 8];
            gload_lds16(g, &Bs[r0 * 32]);
        }
    };

    // ---- phase A: acc = x @ W1^T (K=256) ----
    f32x4 acc[4][4] = {};
    loadX(0);
    stageB(0, smem + 4096);
    writeA(smem);
    __syncthreads();
    for (int k0 = 0; k0 < F_IN; k0 += 32) {
        const int cur = (k0 >> 5) & 1;
        ushort* As = smem + cur * 8192;
        ushort* Bs = As + 4096;
        const bool more = (k0 + 32 < F_IN);
        if (more) {
            stageB(k0 + 32, smem + (cur ^ 1) * 8192 + 4096);
            loadX(k0 + 32);
        }
        bf16x8 af[4], bfr[4];
#pragma unroll
        for (int t4 = 0; t4 < 4; t4++) {
            int ra = wm + t4 * 16 + lr;
            int rb = wn + t4 * 16 + lr;
            af[t4]  = *(bf16x8*)&As[ra * 32 + ((lq ^ ((ra >> 1) & 3)) << 3)];
            bfr[t4] = *(bf16x8*)&Bs[rb * 32 + ((lq ^ ((rb >> 1) & 3)) << 3)];
        }
#pragma unroll
        for (int i = 0; i < 4; i++)
#pragma unroll
            for (int j = 0; j < 4; j++)
                acc[i][j] = __builtin_amdgcn_mfma_f32_16x16x32_bf16(af[i], bfr[j], acc[i][j], 0, 0, 0);
        if (more) writeA(smem + (cur ^ 1) * 8192);
        __syncthreads();
    }

    // prefetch W2 frags for k0=0
    uint4 wb[2][4];
#pragma unroll
    for (int t4 = 0; t4 < 4; t4++)
        wb[0][t4] = *(const uint4*)&W2b[(long)(wn + t4 * 16 + lr) * CCH + lq * 8];

    // ---- epilogue A: h = relu(acc + b1) -> Ht (swizzled) ----
    {
        float bv[4];
#pragma unroll
        for (int j = 0; j < 4; j++) bv[j] = b1[wn + j * 16 + lr];
#pragma unroll
        for (int i = 0; i < 4; i++)
#pragma unroll
            for (int r = 0; r < 4; r++) {
                int row = wm + i * 16 + lq * 4 + r;
                int rx  = (row & 7) << 3;
#pragma unroll
                for (int j = 0; j < 4; j++)
                    Ht[row * 128 + ((wn + j * 16 + lr) ^ rx)] = f2bf(fmaxf(acc[i][j][r] + bv[j], 0.f));
            }
    }
    __syncthreads();

    // ---- phase B: acc2 = h @ W2^T (K=128), barrier-free ----
    f32x4 acc2[4][4] = {};
#pragma unroll
    for (int kk = 0; kk < 4; kk++) {
        const int k0 = kk * 32;
        if (kk < 3) {
#pragma unroll
            for (int t4 = 0; t4 < 4; t4++)
                wb[(kk + 1) & 1][t4] =
                    *(const uint4*)&W2b[(long)(wn + t4 * 16 + lr) * CCH + k0 + 32 + lq * 8];
        }
        bf16x8 af[4];
#pragma unroll
        for (int t4 = 0; t4 < 4; t4++) {
            int ra = wm + t4 * 16 + lr;
            af[t4] = *(bf16x8*)&Ht[ra * 128 + ((k0 + lq * 8) ^ ((ra & 7) << 3))];
        }
#pragma unroll
        for (int i = 0; i < 4; i++)
#pragma unroll
            for (int j = 0; j < 4; j++)
                acc2[i][j] = __builtin_amdgcn_mfma_f32_16x16x32_bf16(af[i], *(bf16x8*)&wb[kk & 1][j],
                                                                     acc2[i][j], 0, 0, 0);
    }
    __syncthreads();

    // ---- epilogue B: z -> Ht (swizzled) -> coalesced store ----
#pragma unroll
    for (int i = 0; i < 4; i++)
#pragma unroll
        for (int r = 0; r < 4; r++) {
            int row = wm + i * 16 + lq * 4 + r;
            int rx  = (row & 7) << 3;
#pragma unroll
            for (int j = 0; j < 4; j++)
                Ht[row * 128 + ((wn + j * 16 + lr) ^ rx)] = f2bf(acc2[i][j][r]);
        }
    __syncthreads();
    {
        int colq = tid & 15, row0 = tid >> 4;
#pragma unroll
        for (int i = 0; i < 8; i++) {
            int row = row0 + i * 16;
            if (m0 + row < M)
                *(uint4*)&Zq[(long)(m0 + row) * CCH + colq * 8] =
                    *(uint4*)&Ht[row * 128 + ((colq * 8) ^ ((row & 7) << 3))];
        }
    }
}

// ---------------- U1: partition (XCD-contiguous chunk remap, FIRST) ∪ gemm half A ----------------
// Remap (bijective, m204-style): XCD x = bid&7 gets a CONTIGUOUS chunk range, so the ~8
// consecutive chunks contributing to any 64B pairs line share one XCD L2 -> single writeback
// (was: 8 XCDs ping-ponging every pairs line). Build blocks first => bid&7 is the XCD key.
__global__ __launch_bounds__(256)
void u_part_gemm(const int* __restrict__ src, const int* __restrict__ dst,
                 const int* __restrict__ histC, const int* __restrict__ prefT,
                 const int* __restrict__ btot, int* __restrict__ gbase,
                 unsigned* __restrict__ pairs, int E, int ncp, int nchunks,
                 const float* __restrict__ X, const ushort* __restrict__ W1b,
                 const ushort* __restrict__ W2b, const float* __restrict__ b1,
                 ushort* __restrict__ Zq, int M)
{
    __shared__ unsigned smem4[8192];    // 32 KB, carved per path
    const int bid = blockIdx.x;
    if (bid < nchunks) {
        const int x = bid & 7, i = bid >> 3;
        const int q = nchunks >> 3, r = nchunks & 7;
        const int chunk = (x < r) ? x * (q + 1) + i : r * (q + 1) + (x - r) * q + i;
        partition_body(smem4, src, dst, histC, prefT, btot, gbase, pairs, E, ncp, chunk);
    } else {
        gemm_body(smem4, X, W1b, W2b, b1, Zq, M, (bid - nchunks) * 128);
    }
}

// ---------------- U2: bucket CSR (FIRST) ∪ gemm half B ----------------
__global__ __launch_bounds__(256)
void u_csr_gemm(const unsigned* __restrict__ pairs, const int* __restrict__ base,
                int* __restrict__ row_start, float* __restrict__ dinv,
                unsigned* __restrict__ csr, int N, int E, int nbuck, int ngA,
                const float* __restrict__ X, const ushort* __restrict__ W1b,
                const ushort* __restrict__ W2b, const float* __restrict__ b1,
                ushort* __restrict__ Zq, int M)
{
    __shared__ unsigned smem4[8192];
    const int bid = blockIdx.x;
    if (bid < nbuck)
        csr_body(smem4, pairs, base, row_start, dinv, csr, N, E, bid, nbuck - 1);
    else
        gemm_body(smem4, X, W1b, W2b, b1, Zq, M, (ngA + bid - nbuck) * 128);
}

// ---------------- K6: gather (dinv[src]*dinv[dst] applied here) ----------------
__global__ __launch_bounds__(256)
void gather_nodes(const unsigned* __restrict__ zq, const unsigned* __restrict__ csr,
                  const int* __restrict__ row_start, const float* __restrict__ dinv,
                  const float* __restrict__ b2, float* __restrict__ out, int N)
{
    const int node = blockIdx.x * 4 + (threadIdx.x >> 6);
    const int lane = threadIdx.x & 63;
    if (node >= N) return;

    const float di = dinv[node];
    float2 zs = bf2f2(zq[(long)node * 64 + lane]);
    float acc0 = di * zs.x, acc1 = di * zs.y;      // self-loop: dinv[d]*z[d]

    const int rs = row_start[node];
    const int re = row_start[node + 1];
    int j = rs;
    for (; j + 8 <= re; j += 8) {
        unsigned sI[8], zv[8];
        float dv[8];
#pragma unroll
        for (int q = 0; q < 8; q++) sI[q] = csr[j + q];
#pragma unroll
        for (int q = 0; q < 8; q++) dv[q] = dinv[sI[q]];
#pragma unroll
        for (int q = 0; q < 8; q++) zv[q] = zq[(long)sI[q] * 64 + lane];
#pragma unroll
        for (int q = 0; q < 8; q++) { float2 f = bf2f2(zv[q]); acc0 += dv[q] * f.x; acc1 += dv[q] * f.y; }
    }
    for (; j < re; j++) {
        unsigned s = csr[j];
        float ds = dinv[s];
        float2 f = bf2f2(zq[(long)s * 64 + lane]);
        acc0 += ds * f.x; acc1 += ds * f.y;
    }

    float2 o;
    o.x = b2[lane * 2 + 0] + di * acc0;
    o.y = b2[lane * 2 + 1] + di * acc1;
    *(float2*)&out[(long)node * CCH + lane * 2] = o;
}

extern "C" void kernel_launch(void* const* d_in, const int* in_sizes, int n_in,
                              void* d_out, int out_size, void* d_ws, size_t ws_size,
                              hipStream_t stream)
{
    const float* x  = (const float*)d_in[0];
    const int*   ei = (const int*)d_in[1];
    const float* W1 = (const float*)d_in[2];
    const float* b1 = (const float*)d_in[3];
    const float* W2 = (const float*)d_in[4];
    const float* b2 = (const float*)d_in[5];
    float* out = (float*)d_out;

    const int N = in_sizes[0] / F_IN;
    const int E = in_sizes[1] / 2;
    const int* src = ei;
    const int* dst = ei + E;

    const int nchunks = (E + CHUNK - 1) / CHUNK;        // 782
    const int ncp     = (nchunks + 63) & ~63;           // 832
    const int nbuck   = (N + BNODES - 1) / BNODES;      // 782
    const int ngrid   = (N + 127) / 128;                // 782
    const int ngA     = (ngrid + 1) / 2;                // 391 (gemm half A)
    const int ngB     = ngrid - ngA;                    // 391 (gemm half B)
    const int ncvt    = (CCH * F_IN + CCH * CCH + 255) / 256;

    char* ws = (char*)d_ws;
    ushort* zq    = (ushort*)ws;   ws += (size_t)N * CCH * 2;
    ushort* w1b   = (ushort*)ws;   ws += (size_t)CCH * F_IN * 2;
    ushort* w2b   = (ushort*)ws;   ws += (size_t)CCH * CCH * 2;
    unsigned* prs = (unsigned*)ws; ws += (size_t)E * 4;
    unsigned* csr = (unsigned*)ws; ws += (size_t)E * 4;
    int* rstart   = (int*)ws;      ws += ((size_t)N + 1) * 4;
    float* dinv   = (float*)ws;    ws += (size_t)N * 4;
    int* histC    = (int*)ws;      ws += (size_t)nchunks * NBUCK * 4;
    int* histT    = (int*)ws;      ws += (size_t)NBUCK * ncp * 4;
    int* prefT    = (int*)ws;      ws += (size_t)NBUCK * ncp * 4;
    int* btot     = (int*)ws;      ws += NBUCK * 4;
    int* gbase    = (int*)ws;      ws += (NBUCK + 1) * 4;

    // K1: histogram (tiled histT) + weight cvt
    hist_cvt<<<nchunks + ncvt, 256, 0, stream>>>(dst, histC, histT, E, nchunks, ncp, W1, W2, w1b, w2b);
    // K2: bucket scan (reads tiled histT)
    scan_buckets<<<NBUCK / 4, 256, 0, stream>>>(histT, prefT, btot, nchunks, ncp);
    // U1: partition (XCD-remapped, first) ∪ gemm-half-A
    u_part_gemm<<<nchunks + ngA, 256, 0, stream>>>(src, dst, histC, prefT, btot, gbase, prs,
                                                   E, ncp, nchunks, x, w1b, w2b, b1, zq, N);
    // U2: bucket-CSR (first) ∪ gemm-half-B
    u_csr_gemm<<<nbuck + ngB, 256, 0, stream>>>(prs, gbase, rstart, dinv, csr, N, E,
                                                nbuck, ngA, x, w1b, w2b, b1, zq, N);
    // K6: aggregate (applies dinv[src] * dinv[dst])
    gather_nodes<<<(N + 3) / 4, 256, 0, stream>>>((const unsigned*)zq, csr, rstart, dinv, b2, out, N);
}